// Round 18
// baseline (41.815 us; speedup 1.0000x reference)
//
#include <hip/hip_runtime.h>
#include <hip/hip_bf16.h>

#define NROWS 8192
#define DIM   128
#define NPAIR (NROWS / 2)
#define CSPLIT 16                        // col chunks -> partial[row][16]
#define COLS_PER_CS (NROWS / CSPLIT)     // 512 cols per block
#define CTILE 64                         // cols per LDS tile (16 KB)
#define NT (COLS_PER_CS / CTILE)         // 8 tiles per chunk
#define MREP 2                           // 16-row tiles per wave -> 32 rows
#define ROWS_PER_BLOCK 128               // 4 waves * 32 rows

typedef __attribute__((ext_vector_type(8))) short bf16x8;
typedef __attribute__((ext_vector_type(4))) float f32x4;

__device__ inline float exp2_fast(float x) {
#if __has_builtin(__builtin_amdgcn_exp2f)
    return __builtin_amdgcn_exp2f(x);
#else
    return exp2f(x);
#endif
}

__device__ inline unsigned short f2bf(float f) {
    unsigned int u = __float_as_uint(f);
    unsigned int r = (u + 0x7fffu + ((u >> 16) & 1u)) >> 16;
    return (unsigned short)r;
}

// exp(d/128 + 1) = e * exp2(SCL*d). ONE array scaled by sqrt(SCL):
// dot(xs,xs) = SCL * dot(x,x). e folded into the partial write.
#define SQRT_SCL_F 0.1061652787362689f   // sqrt(log2(e)/128)
#define E1_F       2.7182818284590452f

// Kernel 1: X (f32) -> Xs (bf16, scaled by sqrt(SCL)). Also zeroes the
// loss-kernel's last-block counter (stream-ordered before k_loss).
__global__ __launch_bounds__(256) void k_convert(const float* __restrict__ X,
                                                 unsigned short* __restrict__ Xs,
                                                 int* __restrict__ counter) {
    int id = blockIdx.x * 256 + threadIdx.x;       // 0 .. 262143
    float4 v = reinterpret_cast<const float4*>(X)[id];
    ushort4 o;
    o.x = f2bf(v.x * SQRT_SCL_F); o.y = f2bf(v.y * SQRT_SCL_F);
    o.z = f2bf(v.z * SQRT_SCL_F); o.w = f2bf(v.w * SQRT_SCL_F);
    reinterpret_cast<ushort4*>(Xs)[id] = o;
    if (id == 0) *counter = 0;
}

// Kernel 2: partial[row][cs] = e * sum over 512-col chunk of exp2(SCL*dot).
// SOURCE BYTE-IDENTICAL to R9/R17 (proven best basin: 41.2-41.6 us total;
// R10-R16 perturbations all regressed -- do not touch). Called with
// Xa == Xc == Xs (read-only aliasing; sqrt-scale on both operands).
__global__ __launch_bounds__(256, 4) void k_rowsum(const unsigned short* __restrict__ Xa,
                                                   const unsigned short* __restrict__ Xc,
                                                   float* __restrict__ partial) {
    __shared__ unsigned short Bt[CTILE * DIM];   // 16 KB
    const int tid  = threadIdx.x;
    const int wave = tid >> 6;
    const int lane = tid & 63;
    const int l15  = lane & 15;
    const int lhi  = lane >> 4;   // 0..3
    const int rowbase = blockIdx.x * ROWS_PER_BLOCK + wave * (MREP * 16);
    const int cs = blockIdx.y;

    // A fragments: 2 row-tiles x 4 k-groups = 32 VGPRs, loaded once, pinned.
    bf16x8 a00, a01, a02, a03, a10, a11, a12, a13;
    {
        const unsigned short* r0 = Xa + (size_t)(rowbase + l15) * DIM + lhi * 8;
        const unsigned short* r1 = r0 + 16 * DIM;
        a00 = *reinterpret_cast<const bf16x8*>(r0);
        a01 = *reinterpret_cast<const bf16x8*>(r0 + 32);
        a02 = *reinterpret_cast<const bf16x8*>(r0 + 64);
        a03 = *reinterpret_cast<const bf16x8*>(r0 + 96);
        a10 = *reinterpret_cast<const bf16x8*>(r1);
        a11 = *reinterpret_cast<const bf16x8*>(r1 + 32);
        a12 = *reinterpret_cast<const bf16x8*>(r1 + 64);
        a13 = *reinterpret_cast<const bf16x8*>(r1 + 96);
    }
    asm volatile("" : "+v"(a00), "+v"(a01), "+v"(a02), "+v"(a03));
    asm volatile("" : "+v"(a10), "+v"(a11), "+v"(a12), "+v"(a13));

    f32x4 esum0 = {0.f, 0.f, 0.f, 0.f};
    f32x4 esum1 = {0.f, 0.f, 0.f, 0.f};

    // Staging geometry: 1024 16B-chunks per tile, 4 per thread.
    const int tcol = tid >> 4;        // 0..15
    const int tseg = tid & 15;
    const unsigned short* gsrc = Xc + (size_t)(cs * COLS_PER_CS + tcol) * DIM + tseg * 8;
    const int lslot = (tcol << 4) | (tseg ^ (tcol & 7));

    // Prologue: issue loads for tile 0.
    bf16x8 st0, st1, st2, st3;
    st0 = *reinterpret_cast<const bf16x8*>(gsrc);
    st1 = *reinterpret_cast<const bf16x8*>(gsrc + 16 * DIM);
    st2 = *reinterpret_cast<const bf16x8*>(gsrc + 32 * DIM);
    st3 = *reinterpret_cast<const bf16x8*>(gsrc + 48 * DIM);

    for (int it = 0; it < NT; ++it) {
        if (it) __syncthreads();     // previous compute done reading LDS
        *reinterpret_cast<bf16x8*>(&Bt[(size_t)(lslot      ) * 8]) = st0;
        *reinterpret_cast<bf16x8*>(&Bt[(size_t)(lslot + 256) * 8]) = st1;
        *reinterpret_cast<bf16x8*>(&Bt[(size_t)(lslot + 512) * 8]) = st2;
        *reinterpret_cast<bf16x8*>(&Bt[(size_t)(lslot + 768) * 8]) = st3;
        __syncthreads();             // tile visible

        if (it + 1 < NT) {           // issue next tile's loads (no wait here)
            const unsigned short* nb = gsrc + (size_t)(it + 1) * CTILE * DIM;
            st0 = *reinterpret_cast<const bf16x8*>(nb);
            st1 = *reinterpret_cast<const bf16x8*>(nb + 16 * DIM);
            st2 = *reinterpret_cast<const bf16x8*>(nb + 32 * DIM);
            st3 = *reinterpret_cast<const bf16x8*>(nb + 48 * DIM);
        }

        const int x = l15 & 7;       // read-side swizzle (same involution)
#pragma unroll
        for (int ct = 0; ct < CTILE / 16; ++ct) {
            const unsigned short* lb = &Bt[(size_t)(ct * 16 + l15) * DIM];
            bf16x8 b0 = *reinterpret_cast<const bf16x8*>(lb + ((lhi      ^ x) * 8));
            bf16x8 b1 = *reinterpret_cast<const bf16x8*>(lb + (((lhi + 4 ) ^ x) * 8));
            bf16x8 b2 = *reinterpret_cast<const bf16x8*>(lb + (((lhi + 8 ) ^ x) * 8));
            bf16x8 b3 = *reinterpret_cast<const bf16x8*>(lb + (((lhi + 12) ^ x) * 8));

            f32x4 d0 = {0.f, 0.f, 0.f, 0.f};
            f32x4 d1 = {0.f, 0.f, 0.f, 0.f};
            d0 = __builtin_amdgcn_mfma_f32_16x16x32_bf16(a00, b0, d0, 0, 0, 0);
            d1 = __builtin_amdgcn_mfma_f32_16x16x32_bf16(a10, b0, d1, 0, 0, 0);
            d0 = __builtin_amdgcn_mfma_f32_16x16x32_bf16(a01, b1, d0, 0, 0, 0);
            d1 = __builtin_amdgcn_mfma_f32_16x16x32_bf16(a11, b1, d1, 0, 0, 0);
            d0 = __builtin_amdgcn_mfma_f32_16x16x32_bf16(a02, b2, d0, 0, 0, 0);
            d1 = __builtin_amdgcn_mfma_f32_16x16x32_bf16(a12, b2, d1, 0, 0, 0);
            d0 = __builtin_amdgcn_mfma_f32_16x16x32_bf16(a03, b3, d0, 0, 0, 0);
            d1 = __builtin_amdgcn_mfma_f32_16x16x32_bf16(a13, b3, d1, 0, 0, 0);

            esum0[0] += exp2_fast(d0[0]); esum0[1] += exp2_fast(d0[1]);
            esum0[2] += exp2_fast(d0[2]); esum0[3] += exp2_fast(d0[3]);
            esum1[0] += exp2_fast(d1[0]); esum1[1] += exp2_fast(d1[1]);
            esum1[2] += exp2_fast(d1[2]); esum1[3] += exp2_fast(d1[3]);
        }
    }

    // Reduce the 16 column-lanes (varying l15); one slot per row.
#pragma unroll
    for (int m = 0; m < MREP; ++m) {
#pragma unroll
        for (int j = 0; j < 4; ++j) {
            float v = (m == 0) ? esum0[j] : esum1[j];
            v += __shfl_xor(v, 1, 64);
            v += __shfl_xor(v, 2, 64);
            v += __shfl_xor(v, 4, 64);
            v += __shfl_xor(v, 8, 64);
            if (l15 == 0) {
                int row = rowbase + m * 16 + lhi * 4 + j;
                partial[(size_t)row * CSPLIT + cs] = v * E1_F;
            }
        }
    }
}

// Kernel 3 (FUSED epilogue): per-pair exact f32 2x2 block + D_pos + J^2,
// block-reduced; last block (device-scope atomic + fences, fixed order
// -> deterministic) sums the 16 partials and writes the loss.
__global__ __launch_bounds__(256) void k_loss(const float* __restrict__ X,
                                              const float* __restrict__ partial,
                                              float* __restrict__ lpart,
                                              int* __restrict__ counter,
                                              float* __restrict__ out) {
    int p = blockIdx.x * 256 + threadIdx.x;   // 0..4095
    const float4* a = reinterpret_cast<const float4*>(X + (size_t)(2 * p) * DIM);
    const float4* b = reinterpret_cast<const float4*>(X + (size_t)(2 * p + 1) * DIM);
    float d00 = 0.f, d01 = 0.f, d11 = 0.f;
#pragma unroll 8
    for (int i = 0; i < DIM / 4; ++i) {
        float4 av = a[i], bv = b[i];
        d00 += av.x * av.x + av.y * av.y + av.z * av.z + av.w * av.w;
        d01 += av.x * bv.x + av.y * bv.y + av.z * bv.z + av.w * bv.w;
        d11 += bv.x * bv.x + bv.y * bv.y + bv.z * bv.z + bv.w * bv.w;
    }
    float D01 = d01 * (1.0f / DIM);
    float blocksum = __expf(d00 * (1.0f / DIM) + 1.0f)
                   + 2.0f * __expf(D01 + 1.0f)
                   + __expf(d11 * (1.0f / DIM) + 1.0f);

    const float4* pp = reinterpret_cast<const float4*>(partial + (size_t)(2 * p) * CSPLIT);
    float S = 0.0f;
#pragma unroll
    for (int i = 0; i < 2 * CSPLIT / 4; ++i) {
        float4 v = pp[i];
        S += v.x + v.y + v.z + v.w;
    }
    S -= blocksum;
    float J = logf(1e-8f + S) - D01;
    float t = fmaxf(J, 0.0f);
    float acc = t * t;

    __shared__ float red[4];
    float v = acc;
#pragma unroll
    for (int off = 32; off >= 1; off >>= 1) v += __shfl_down(v, off, 64);
    if ((threadIdx.x & 63) == 0) red[threadIdx.x >> 6] = v;
    __syncthreads();
    if (threadIdx.x == 0) {
        lpart[blockIdx.x] = red[0] + red[1] + red[2] + red[3];
        __threadfence();                         // release lpart write
        int old = atomicAdd(counter, 1);         // device-scope
        if (old == (NPAIR / 256) - 1) {          // last block
            __threadfence();                     // acquire others' lparts
            const volatile float* vp = lpart;
            float s = 0.0f;
            for (int i = 0; i < NPAIR / 256; ++i) s += vp[i];
            out[0] = s * (1.0f / (2.0f * NPAIR));
            *counter = 0;                        // reset for next replay
        }
    }
}

extern "C" void kernel_launch(void* const* d_in, const int* in_sizes, int n_in,
                              void* d_out, int out_size, void* d_ws, size_t ws_size,
                              hipStream_t stream) {
    const float* X = (const float*)d_in[0];
    float* out = (float*)d_out;

    unsigned short* Xs = (unsigned short*)d_ws;                        // 2 MB
    float* partial = (float*)(Xs + (size_t)NROWS * DIM);               // 512 KB
    float* lpart = partial + (size_t)NROWS * CSPLIT;                   // 64 B
    int* counter = (int*)(lpart + 16);                                 // 4 B

    k_convert<<<dim3((NROWS * DIM / 4) / 256), dim3(256), 0, stream>>>(X, Xs, counter);
    k_rowsum<<<dim3(NROWS / ROWS_PER_BLOCK, CSPLIT), dim3(256), 0, stream>>>(Xs, Xs, partial);
    k_loss<<<dim3(NPAIR / 256), dim3(256), 0, stream>>>(X, partial, lpart, counter, out);
}

// Round 19
// 38.937 us; speedup vs baseline: 1.0739x; 1.0739x over previous
//
#include <hip/hip_runtime.h>
#include <hip/hip_bf16.h>

#define NROWS 8192
#define DIM   128
#define NPAIR (NROWS / 2)
#define CSPLIT 16                        // col chunks -> partial[row][16]
#define COLS_PER_CS (NROWS / CSPLIT)     // 512 cols per block
#define CTILE 64                         // cols per LDS tile (16 KB)
#define NT (COLS_PER_CS / CTILE)         // 8 tiles per chunk
#define MREP 2                           // 16-row tiles per wave -> 32 rows
#define ROWS_PER_BLOCK 128               // 4 waves * 32 rows
#define LOSS_BLOCKS (NPAIR / 16)         // 256 blocks, 16 pairs each

typedef __attribute__((ext_vector_type(8))) short bf16x8;
typedef __attribute__((ext_vector_type(4))) float f32x4;

__device__ inline float exp2_fast(float x) {
#if __has_builtin(__builtin_amdgcn_exp2f)
    return __builtin_amdgcn_exp2f(x);
#else
    return exp2f(x);
#endif
}

__device__ inline unsigned short f2bf(float f) {
    unsigned int u = __float_as_uint(f);
    unsigned int r = (u + 0x7fffu + ((u >> 16) & 1u)) >> 16;
    return (unsigned short)r;
}

// exp(d/128 + 1) = e * exp2(SCL*d). ONE array scaled by sqrt(SCL):
// dot(xs,xs) = SCL * dot(x,x). e folded into the partial write.
#define SQRT_SCL_F 0.1061652787362689f   // sqrt(log2(e)/128)
#define E1_F       2.7182818284590452f

// Kernel 1: X (f32) -> Xs (bf16, scaled by sqrt(SCL)). Also zeroes the
// loss-kernel's last-block counter (stream-ordered before k_loss).
__global__ __launch_bounds__(256) void k_convert(const float* __restrict__ X,
                                                 unsigned short* __restrict__ Xs,
                                                 int* __restrict__ counter) {
    int id = blockIdx.x * 256 + threadIdx.x;       // 0 .. 262143
    float4 v = reinterpret_cast<const float4*>(X)[id];
    ushort4 o;
    o.x = f2bf(v.x * SQRT_SCL_F); o.y = f2bf(v.y * SQRT_SCL_F);
    o.z = f2bf(v.z * SQRT_SCL_F); o.w = f2bf(v.w * SQRT_SCL_F);
    reinterpret_cast<ushort4*>(Xs)[id] = o;
    if (id == 0) *counter = 0;
}

// Kernel 2: partial[row][cs] = e * sum over 512-col chunk of exp2(SCL*dot).
// SOURCE BYTE-IDENTICAL to R9/R17/R18 (proven best basin: 41.2-41.8 us;
// R10-R16 perturbations all regressed -- do not touch). Called with
// Xa == Xc == Xs (read-only aliasing; sqrt-scale on both operands).
__global__ __launch_bounds__(256, 4) void k_rowsum(const unsigned short* __restrict__ Xa,
                                                   const unsigned short* __restrict__ Xc,
                                                   float* __restrict__ partial) {
    __shared__ unsigned short Bt[CTILE * DIM];   // 16 KB
    const int tid  = threadIdx.x;
    const int wave = tid >> 6;
    const int lane = tid & 63;
    const int l15  = lane & 15;
    const int lhi  = lane >> 4;   // 0..3
    const int rowbase = blockIdx.x * ROWS_PER_BLOCK + wave * (MREP * 16);
    const int cs = blockIdx.y;

    // A fragments: 2 row-tiles x 4 k-groups = 32 VGPRs, loaded once, pinned.
    bf16x8 a00, a01, a02, a03, a10, a11, a12, a13;
    {
        const unsigned short* r0 = Xa + (size_t)(rowbase + l15) * DIM + lhi * 8;
        const unsigned short* r1 = r0 + 16 * DIM;
        a00 = *reinterpret_cast<const bf16x8*>(r0);
        a01 = *reinterpret_cast<const bf16x8*>(r0 + 32);
        a02 = *reinterpret_cast<const bf16x8*>(r0 + 64);
        a03 = *reinterpret_cast<const bf16x8*>(r0 + 96);
        a10 = *reinterpret_cast<const bf16x8*>(r1);
        a11 = *reinterpret_cast<const bf16x8*>(r1 + 32);
        a12 = *reinterpret_cast<const bf16x8*>(r1 + 64);
        a13 = *reinterpret_cast<const bf16x8*>(r1 + 96);
    }
    asm volatile("" : "+v"(a00), "+v"(a01), "+v"(a02), "+v"(a03));
    asm volatile("" : "+v"(a10), "+v"(a11), "+v"(a12), "+v"(a13));

    f32x4 esum0 = {0.f, 0.f, 0.f, 0.f};
    f32x4 esum1 = {0.f, 0.f, 0.f, 0.f};

    // Staging geometry: 1024 16B-chunks per tile, 4 per thread.
    const int tcol = tid >> 4;        // 0..15
    const int tseg = tid & 15;
    const unsigned short* gsrc = Xc + (size_t)(cs * COLS_PER_CS + tcol) * DIM + tseg * 8;
    const int lslot = (tcol << 4) | (tseg ^ (tcol & 7));

    // Prologue: issue loads for tile 0.
    bf16x8 st0, st1, st2, st3;
    st0 = *reinterpret_cast<const bf16x8*>(gsrc);
    st1 = *reinterpret_cast<const bf16x8*>(gsrc + 16 * DIM);
    st2 = *reinterpret_cast<const bf16x8*>(gsrc + 32 * DIM);
    st3 = *reinterpret_cast<const bf16x8*>(gsrc + 48 * DIM);

    for (int it = 0; it < NT; ++it) {
        if (it) __syncthreads();     // previous compute done reading LDS
        *reinterpret_cast<bf16x8*>(&Bt[(size_t)(lslot      ) * 8]) = st0;
        *reinterpret_cast<bf16x8*>(&Bt[(size_t)(lslot + 256) * 8]) = st1;
        *reinterpret_cast<bf16x8*>(&Bt[(size_t)(lslot + 512) * 8]) = st2;
        *reinterpret_cast<bf16x8*>(&Bt[(size_t)(lslot + 768) * 8]) = st3;
        __syncthreads();             // tile visible

        if (it + 1 < NT) {           // issue next tile's loads (no wait here)
            const unsigned short* nb = gsrc + (size_t)(it + 1) * CTILE * DIM;
            st0 = *reinterpret_cast<const bf16x8*>(nb);
            st1 = *reinterpret_cast<const bf16x8*>(nb + 16 * DIM);
            st2 = *reinterpret_cast<const bf16x8*>(nb + 32 * DIM);
            st3 = *reinterpret_cast<const bf16x8*>(nb + 48 * DIM);
        }

        const int x = l15 & 7;       // read-side swizzle (same involution)
#pragma unroll
        for (int ct = 0; ct < CTILE / 16; ++ct) {
            const unsigned short* lb = &Bt[(size_t)(ct * 16 + l15) * DIM];
            bf16x8 b0 = *reinterpret_cast<const bf16x8*>(lb + ((lhi      ^ x) * 8));
            bf16x8 b1 = *reinterpret_cast<const bf16x8*>(lb + (((lhi + 4 ) ^ x) * 8));
            bf16x8 b2 = *reinterpret_cast<const bf16x8*>(lb + (((lhi + 8 ) ^ x) * 8));
            bf16x8 b3 = *reinterpret_cast<const bf16x8*>(lb + (((lhi + 12) ^ x) * 8));

            f32x4 d0 = {0.f, 0.f, 0.f, 0.f};
            f32x4 d1 = {0.f, 0.f, 0.f, 0.f};
            d0 = __builtin_amdgcn_mfma_f32_16x16x32_bf16(a00, b0, d0, 0, 0, 0);
            d1 = __builtin_amdgcn_mfma_f32_16x16x32_bf16(a10, b0, d1, 0, 0, 0);
            d0 = __builtin_amdgcn_mfma_f32_16x16x32_bf16(a01, b1, d0, 0, 0, 0);
            d1 = __builtin_amdgcn_mfma_f32_16x16x32_bf16(a11, b1, d1, 0, 0, 0);
            d0 = __builtin_amdgcn_mfma_f32_16x16x32_bf16(a02, b2, d0, 0, 0, 0);
            d1 = __builtin_amdgcn_mfma_f32_16x16x32_bf16(a12, b2, d1, 0, 0, 0);
            d0 = __builtin_amdgcn_mfma_f32_16x16x32_bf16(a03, b3, d0, 0, 0, 0);
            d1 = __builtin_amdgcn_mfma_f32_16x16x32_bf16(a13, b3, d1, 0, 0, 0);

            esum0[0] += exp2_fast(d0[0]); esum0[1] += exp2_fast(d0[1]);
            esum0[2] += exp2_fast(d0[2]); esum0[3] += exp2_fast(d0[3]);
            esum1[0] += exp2_fast(d1[0]); esum1[1] += exp2_fast(d1[1]);
            esum1[2] += exp2_fast(d1[2]); esum1[3] += exp2_fast(d1[3]);
        }
    }

    // Reduce the 16 column-lanes (varying l15); one slot per row.
#pragma unroll
    for (int m = 0; m < MREP; ++m) {
#pragma unroll
        for (int j = 0; j < 4; ++j) {
            float v = (m == 0) ? esum0[j] : esum1[j];
            v += __shfl_xor(v, 1, 64);
            v += __shfl_xor(v, 2, 64);
            v += __shfl_xor(v, 4, 64);
            v += __shfl_xor(v, 8, 64);
            if (l15 == 0) {
                int row = rowbase + m * 16 + lhi * 4 + j;
                partial[(size_t)row * CSPLIT + cs] = v * E1_F;
            }
        }
    }
}

// Kernel 3 (PARALLEL epilogue, 16 lanes/pair, 256 blocks): exact f32 2x2
// block + D_pos + J^2 per pair; deterministic fixed-order reductions;
// last block (atomic counter + fences) does the final 256-way sum.
__global__ __launch_bounds__(256) void k_loss(const float* __restrict__ X,
                                              const float* __restrict__ partial,
                                              float* __restrict__ lpart,
                                              int* __restrict__ counter,
                                              float* __restrict__ out) {
    const int tid = threadIdx.x;
    const int g   = tid >> 4;                 // pair within block, 0..15
    const int sub = tid & 15;
    const int p   = blockIdx.x * 16 + g;      // 0..4095

    // 16 lanes per pair: lane sub covers elements [sub*8, sub*8+8).
    const float4* a = reinterpret_cast<const float4*>(X + (size_t)(2 * p) * DIM) + sub * 2;
    const float4* b = reinterpret_cast<const float4*>(X + (size_t)(2 * p + 1) * DIM) + sub * 2;
    float d00 = 0.f, d01 = 0.f, d11 = 0.f;
#pragma unroll
    for (int i = 0; i < 2; ++i) {
        float4 av = a[i], bv = b[i];
        d00 += av.x * av.x + av.y * av.y + av.z * av.z + av.w * av.w;
        d01 += av.x * bv.x + av.y * bv.y + av.z * bv.z + av.w * bv.w;
        d11 += bv.x * bv.x + bv.y * bv.y + bv.z * bv.z + bv.w * bv.w;
    }
    // Partial row sums: 2*CSPLIT = 32 floats = 8 float4; lanes 0..7 take one each.
    const float4* pp = reinterpret_cast<const float4*>(partial + (size_t)(2 * p) * CSPLIT);
    float Sp = 0.0f;
    if (sub < 8) { float4 v = pp[sub]; Sp = v.x + v.y + v.z + v.w; }

    // Butterfly reduce within the 16-lane group (stays inside the group).
#pragma unroll
    for (int off = 1; off < 16; off <<= 1) {
        d00 += __shfl_xor(d00, off, 64);
        d01 += __shfl_xor(d01, off, 64);
        d11 += __shfl_xor(d11, off, 64);
        Sp  += __shfl_xor(Sp,  off, 64);
    }

    float D01 = d01 * (1.0f / DIM);
    float blocksum = __expf(d00 * (1.0f / DIM) + 1.0f)
                   + 2.0f * __expf(D01 + 1.0f)
                   + __expf(d11 * (1.0f / DIM) + 1.0f);
    float S = Sp - blocksum;
    float J = logf(1e-8f + S) - D01;
    float t = fmaxf(J, 0.0f);
    float acc = (sub == 0) ? t * t : 0.0f;

    // Sum the 4 group-leaders in each wave, then across the 4 waves.
    acc += __shfl_xor(acc, 16, 64);
    acc += __shfl_xor(acc, 32, 64);
    __shared__ float red[4];
    if ((tid & 63) == 0) red[tid >> 6] = acc;
    __syncthreads();

    __shared__ int isLast;
    if (tid == 0) {
        lpart[blockIdx.x] = red[0] + red[1] + red[2] + red[3];
        __threadfence();                          // release lpart write
        int old = atomicAdd(counter, 1);          // device scope
        isLast = (old == LOSS_BLOCKS - 1);
    }
    __syncthreads();
    if (isLast) {
        __threadfence();                          // acquire others' lparts
        const volatile float* vp = lpart;
        float v = vp[tid];                        // 256 values, one per thread
#pragma unroll
        for (int off = 32; off >= 1; off >>= 1) v += __shfl_down(v, off, 64);
        if ((tid & 63) == 0) red[tid >> 6] = v;
        __syncthreads();
        if (tid == 0) {
            out[0] = (red[0] + red[1] + red[2] + red[3]) * (1.0f / (2.0f * NPAIR));
            *counter = 0;                         // reset for next replay
        }
    }
}

extern "C" void kernel_launch(void* const* d_in, const int* in_sizes, int n_in,
                              void* d_out, int out_size, void* d_ws, size_t ws_size,
                              hipStream_t stream) {
    const float* X = (const float*)d_in[0];
    float* out = (float*)d_out;

    unsigned short* Xs = (unsigned short*)d_ws;                        // 2 MB
    float* partial = (float*)(Xs + (size_t)NROWS * DIM);               // 512 KB
    float* lpart = partial + (size_t)NROWS * CSPLIT;                   // 1 KB
    int* counter = (int*)(lpart + LOSS_BLOCKS);                        // 4 B

    k_convert<<<dim3((NROWS * DIM / 4) / 256), dim3(256), 0, stream>>>(X, Xs, counter);
    k_rowsum<<<dim3(NROWS / ROWS_PER_BLOCK, CSPLIT), dim3(256), 0, stream>>>(Xs, Xs, partial);
    k_loss<<<dim3(LOSS_BLOCKS), dim3(256), 0, stream>>>(X, partial, lpart, counter, out);
}